// Round 3
// baseline (224.427 us; speedup 1.0000x reference)
//
#include <hip/hip_runtime.h>
#include <math.h>

typedef _Float16 half8 __attribute__((ext_vector_type(8)));
typedef float f32x4 __attribute__((ext_vector_type(4)));

#define AS1 __attribute__((address_space(1)))
#define AS3 __attribute__((address_space(3)))

#define BTOT   65536
#define DDIM   256
#define KC     1024

// ---------------- ||e_k||^2 ----------------
__global__ void vq_e2(const float* __restrict__ embed, float* __restrict__ e2g) {
    int gt = blockIdx.x * blockDim.x + threadIdx.x;
    int k = gt >> 6;
    int lane = gt & 63;
    float4 v = *(const float4*)(embed + (size_t)k * DDIM + lane * 4);
    float s = v.x * v.x + v.y * v.y + v.z * v.z + v.w * v.w;
    #pragma unroll
    for (int off = 1; off < 64; off <<= 1) s += __shfl_xor(s, off);
    if (lane == 0) e2g[k] = s;
}

// ---------------- prep: embed -> fp16 hi/lo pre-swizzled image in ws -------
// 64 chunks of 16384B. chunk = kc*8 + p*4 + q  (kc 0..7, p: 0=hi 1=lo, q: col
// quarter). Within chunk: local col cl(0..255)*64B; 16B slot s (k-offsets
// s*8..s*8+8 of this kc's 32) stored at position (s ^ ((cl>>1)&3))*16.
__global__ void vq_prep(const float* __restrict__ embed, char* __restrict__ wsB) {
    int id = blockIdx.x * 256 + threadIdx.x;   // 32768 total
    int c  = id >> 5;          // 0..1023
    int kc = (id >> 2) & 7;    // 0..7
    int s  = id & 3;           // 0..3
    const float* src = embed + (size_t)c * DDIM + kc * 32 + s * 8;
    half8 hi, lo;
    #pragma unroll
    for (int j = 0; j < 8; ++j) {
        float xv = src[j];
        _Float16 hh = (_Float16)xv;
        hi[j] = hh;
        lo[j] = (_Float16)(xv - (float)hh);
    }
    int q = c >> 8, cl = c & 255;
    int inner = cl * 64 + ((s ^ ((cl >> 1) & 3)) << 4);
    *(half8*)(wsB + (size_t)(kc * 8 + q) * 16384 + inner) = hi;
    *(half8*)(wsB + (size_t)(kc * 8 + 4 + q) * 16384 + inner) = lo;
}

// ---------------- main fused MFMA GEMM + softmax/argmax ----------------
__global__ __launch_bounds__(512, 2)
void vq_main(const float* __restrict__ z, const char* __restrict__ wsB,
             const float* __restrict__ e2g, float* __restrict__ psum_g,
             float* __restrict__ counts_g, float* __restrict__ distsum_g,
             float* __restrict__ codes_f_out)
{
    __shared__ __align__(16) char ldsA[65536];     // A hi at 0, lo at 32768
    __shared__ __align__(16) char ldsBraw[65536];  // 4 x 16KB B stages
    // epilogue views (ldsB dead after K-loop):
    float* lmax     = (float*)ldsBraw;             // [64][8]
    int*   larg     = (int*)(ldsBraw + 2048);      // [64][8]
    float* lsum     = (float*)(ldsBraw + 4096);    // [64][8]
    float* rowM     = (float*)(ldsBraw + 6144);    // [64]
    float* rowInv   = (float*)(ldsBraw + 6400);    // [64]
    float* psum_lds = (float*)(ldsBraw + 8192);    // [1024]

    const int tid  = threadIdx.x;
    const int w    = tid >> 6;
    const int lane = tid & 63;
    const int row0 = blockIdx.x * 64;
    // swizzled fragment base (slot = (lane>>4) ^ ((lane>>1)&3)):
    const int swz   = ((lane >> 4) ^ ((lane >> 1) & 3)) << 4;
    const int aBase = (lane & 15) * 64 + swz;
    const int bBase = w * 2048 + (lane & 15) * 64 + swz;

    // ---- issue prefetch for stages 0,1,2 (overlaps A staging) ----
    #pragma unroll
    for (int ps = 0; ps < 3; ++ps) {
        const char* gs = wsB + (size_t)ps * 16384 + tid * 16;
        char* ld = ldsBraw + ps * 16384 + tid * 16;
        __builtin_amdgcn_global_load_lds((AS1 const void*)gs, (AS3 void*)ld, 16, 0, 0);
        __builtin_amdgcn_global_load_lds((AS1 const void*)(gs + 8192),
                                         (AS3 void*)(ld + 8192), 16, 0, 0);
    }

    // ---- A staging: 64 rows of z -> fp16 hi/lo swizzled in LDS ----
    {
        const int ar = tid >> 3;     // row 0..63
        const int kc = tid & 7;      // k-chunk
        const float* src = z + (size_t)(row0 + ar) * DDIM + kc * 32;
        float x[32];
        #pragma unroll
        for (int j = 0; j < 8; ++j) {
            float4 v = ((const float4*)src)[j];
            x[4*j] = v.x; x[4*j+1] = v.y; x[4*j+2] = v.z; x[4*j+3] = v.w;
        }
        float zsq = 0.f;
        #pragma unroll
        for (int j = 0; j < 32; ++j) zsq = fmaf(x[j], x[j], zsq);
        #pragma unroll
        for (int off = 1; off < 64; off <<= 1) zsq += __shfl_xor(zsq, off);
        if (lane == 0) atomicAdd(distsum_g, zsq);   // sum ||z||^2 contribution
        #pragma unroll
        for (int s = 0; s < 4; ++s) {
            half8 hi, lo;
            #pragma unroll
            for (int j = 0; j < 8; ++j) {
                float xv = x[8*s + j];
                _Float16 hh = (_Float16)xv;
                hi[j] = hh;
                lo[j] = (_Float16)(xv - (float)hh);
            }
            int off = kc * 4096 + ar * 64 + ((s ^ ((ar >> 1) & 3)) << 4);
            *(half8*)(ldsA + off) = hi;
            *(half8*)(ldsA + 32768 + off) = lo;
        }
    }
    __syncthreads();   // A visible; stage-0..2 loads also drained (one-time)

    f32x4 acc[4][8];
    #pragma unroll
    for (int rt = 0; rt < 4; ++rt)
        #pragma unroll
        for (int cg = 0; cg < 8; ++cg)
            acc[rt][cg] = (f32x4){0.f, 0.f, 0.f, 0.f};

    half8 aHi[4], aLo[4];

    // 64 stages: s = kc*8 + p*4 + q. Counted-vmcnt depth-3 pipeline:
    // [wait own loads for s][barrier][issue s+3][ds_read + MFMA]
    #pragma unroll
    for (int s = 0; s < 64; ++s) {
        const int kc = s >> 3, p = (s >> 2) & 1, q = s & 3;
        if (s < 62)      asm volatile("s_waitcnt vmcnt(4)\n\ts_barrier" ::: "memory");
        else if (s == 62) asm volatile("s_waitcnt vmcnt(2)\n\ts_barrier" ::: "memory");
        else              asm volatile("s_waitcnt vmcnt(0)\n\ts_barrier" ::: "memory");
        if (s + 3 < 64) {
            const char* gs = wsB + (size_t)(s + 3) * 16384 + tid * 16;
            char* ld = ldsBraw + ((s + 3) & 3) * 16384 + tid * 16;
            __builtin_amdgcn_global_load_lds((AS1 const void*)gs, (AS3 void*)ld, 16, 0, 0);
            __builtin_amdgcn_global_load_lds((AS1 const void*)(gs + 8192),
                                             (AS3 void*)(ld + 8192), 16, 0, 0);
        }
        if (p == 0 && q == 0) {
            #pragma unroll
            for (int rt = 0; rt < 4; ++rt) {
                aHi[rt] = *(const half8*)(ldsA + kc * 4096 + rt * 1024 + aBase);
                aLo[rt] = *(const half8*)(ldsA + 32768 + kc * 4096 + rt * 1024 + aBase);
            }
        }
        const char* bb = ldsBraw + (s & 3) * 16384 + bBase;
        #pragma unroll
        for (int ct = 0; ct < 2; ++ct) {
            half8 bf = *(const half8*)(bb + ct * 1024);
            const int cg = q * 2 + ct;
            #pragma unroll
            for (int rt = 0; rt < 4; ++rt) {
                acc[rt][cg] = __builtin_amdgcn_mfma_f32_16x16x32_f16(
                    aHi[rt], bf, acc[rt][cg], 0, 0, 0);
                if (p == 0)
                    acc[rt][cg] = __builtin_amdgcn_mfma_f32_16x16x32_f16(
                        aLo[rt], bf, acc[rt][cg], 0, 0, 0);
            }
        }
    }
    __syncthreads();   // all stage reads done; ldsB region reusable

    // ---- epilogue ----
    // wave w owns cols: cg -> (cg>>1)*256 + w*32 + (cg&1)*16 + (lane&15)
    // C/D layout: col = lane&15, row = (lane>>4)*4 + i
    int colv[8];
    float e2v[8];
    #pragma unroll
    for (int cg = 0; cg < 8; ++cg) {
        colv[cg] = (cg >> 1) * 256 + w * 32 + (cg & 1) * 16 + (lane & 15);
        e2v[cg] = e2g[colv[cg]];
    }
    psum_lds[tid] = 0.f;
    psum_lds[tid + 512] = 0.f;
    // pass 1: per-wave local max/argmax per row
    #pragma unroll
    for (int rt = 0; rt < 4; ++rt) {
        #pragma unroll
        for (int i = 0; i < 4; ++i) {
            float m = -INFINITY; int am = 0x7fffffff;
            #pragma unroll
            for (int cg = 0; cg < 8; ++cg) {
                float l = fmaf(2.f, acc[rt][cg][i], -e2v[cg]);
                if (l > m) { m = l; am = colv[cg]; }
            }
            #pragma unroll
            for (int off = 1; off < 16; off <<= 1) {
                float om = __shfl_xor(m, off);
                int   oa = __shfl_xor(am, off);
                if (om > m || (om == m && oa < am)) { m = om; am = oa; }
            }
            if ((lane & 15) == 0) {
                int r = rt * 16 + ((lane >> 4) << 2) + i;
                lmax[r * 8 + w] = m; larg[r * 8 + w] = am;
            }
        }
    }
    __syncthreads();
    // pass 2: cross-wave reduce; codes, counts, -sum(max logit)
    if (tid < 64) {
        float M = -INFINITY; int A = 0x7fffffff;
        #pragma unroll
        for (int ww = 0; ww < 8; ++ww) {
            float mm = lmax[tid * 8 + ww]; int aa = larg[tid * 8 + ww];
            if (mm > M || (mm == M && aa < A)) { M = mm; A = aa; }
        }
        rowM[tid] = M;
        codes_f_out[row0 + tid] = (float)A;
        atomicAdd(&counts_g[A], 1.0f);
        float negm = -M;
        #pragma unroll
        for (int off = 1; off < 64; off <<= 1) negm += __shfl_xor(negm, off);
        if (tid == 0) atomicAdd(distsum_g, negm);
    }
    __syncthreads();
    // pass 3: exp and per-wave row sums
    #pragma unroll
    for (int rt = 0; rt < 4; ++rt) {
        #pragma unroll
        for (int i = 0; i < 4; ++i) {
            const int r = rt * 16 + ((lane >> 4) << 2) + i;
            float M = rowM[r];
            float ss = 0.f;
            #pragma unroll
            for (int cg = 0; cg < 8; ++cg) {
                float e = __expf(fmaf(2.f, acc[rt][cg][i], -e2v[cg]) - M);
                acc[rt][cg][i] = e;
                ss += e;
            }
            #pragma unroll
            for (int off = 1; off < 16; off <<= 1) ss += __shfl_xor(ss, off);
            if ((lane & 15) == 0) lsum[r * 8 + w] = ss;
        }
    }
    __syncthreads();
    // pass 4: row denominators
    if (tid < 64) {
        float S = 0.f;
        #pragma unroll
        for (int ww = 0; ww < 8; ++ww) S += lsum[tid * 8 + ww];
        rowInv[tid] = 1.0f / S;
    }
    __syncthreads();
    // pass 5: per-code prob sums
    #pragma unroll
    for (int cg = 0; cg < 8; ++cg) {
        float cp = 0.f;
        #pragma unroll
        for (int rt = 0; rt < 4; ++rt)
            #pragma unroll
            for (int i = 0; i < 4; ++i)
                cp = fmaf(acc[rt][cg][i], rowInv[rt * 16 + ((lane >> 4) << 2) + i], cp);
        atomicAdd(&psum_lds[colv[cg]], cp);
    }
    __syncthreads();
    atomicAdd(&psum_g[tid], psum_lds[tid]);
    atomicAdd(&psum_g[tid + 512], psum_lds[tid + 512]);
}

// ---------------- gather z_q = embed[codes] ----------------
__global__ void vq_gather(const float* __restrict__ embed,
                          const float* __restrict__ codes_f,
                          float* __restrict__ outq)
{
    int idx = blockIdx.x * 256 + threadIdx.x;   // [0, 4194304)
    int b = idx >> 6;
    int c = (int)codes_f[b];
    ((float4*)outq)[idx] = ((const float4*)embed)[(c << 6) + (idx & 63)];
}

// ---------------- finalize scalars ----------------
__global__ void vq_finalize(const float* __restrict__ psum_g,
                            const float* __restrict__ counts_g,
                            const float* __restrict__ distsum_g,
                            float* __restrict__ out_s)
{
    __shared__ float s1[16], s2[16];
    int tid = threadIdx.x;           // 1024 threads
    float a = psum_g[tid] * (1.0f / 65536.0f);
    float e1 = -a * logf(a + 1e-10f);
    float h = counts_g[tid] * (1.0f / 65536.0f);
    float e2 = -h * logf(h + 1e-10f);
    #pragma unroll
    for (int off = 1; off < 64; off <<= 1) {
        e1 += __shfl_xor(e1, off);
        e2 += __shfl_xor(e2, off);
    }
    int w = tid >> 6, lane = tid & 63;
    if (lane == 0) { s1[w] = e1; s2[w] = e2; }
    __syncthreads();
    if (tid == 0) {
        float E1 = 0.0f, E2 = 0.0f;
        #pragma unroll
        for (int i = 0; i < 16; ++i) { E1 += s1[i]; E2 += s2[i]; }
        float commit = distsum_g[0] * (1.0f / 16777216.0f);
        out_s[0] = commit;
        out_s[1] = commit;
        out_s[2] = -E1 / 6.9314718055994531f;
        out_s[3] = E1;
        out_s[4] = __expf(E2);
    }
}

extern "C" void kernel_launch(void* const* d_in, const int* in_sizes, int n_in,
                              void* d_out, int out_size, void* d_ws, size_t ws_size,
                              hipStream_t stream) {
    const float* z     = (const float*)d_in[0];
    const float* embed = (const float*)d_in[1];

    float* out      = (float*)d_out;
    float* zq_out   = out;                  // 16777216
    float* codes_f  = out + 16777216;       // 65536
    float* scalars  = out + 16842752;       // 5

    float* ws        = (float*)d_ws;
    float* psum_g    = ws;                  // 1024
    float* counts_g  = ws + 1024;           // 1024
    float* e2g       = ws + 2048;           // 1024
    float* distsum_g = ws + 3072;           // 1
    char*  wsB       = (char*)d_ws + 16384; // 1 MB fp16 image

    hipMemsetAsync(d_ws, 0, 3080 * sizeof(float), stream);
    vq_prep<<<128, 256, 0, stream>>>(embed, wsB);
    vq_e2<<<256, 256, 0, stream>>>(embed, e2g);
    vq_main<<<BTOT / 64, 512, 0, stream>>>(z, wsB, e2g, psum_g, counts_g,
                                           distsum_g, codes_f);
    vq_gather<<<4194304 / 256, 256, 0, stream>>>(embed, codes_f, zq_out);
    vq_finalize<<<1, 1024, 0, stream>>>(psum_g, counts_g, distsum_g, scalars);
}